// Round 2
// baseline (1755.297 us; speedup 1.0000x reference)
//
#include <hip/hip_runtime.h>
#include <string.h>

#define D_ 128
#define P_ 3600
#define N_ 57600
#define C_ 19
#define NB 2
#define NSPLIT 17
#define TOTCH 450    // 57600/128 column chunks
#define PT 29        // ceil(3600/128)

typedef short bf16x8 __attribute__((ext_vector_type(8)));
typedef float f32x4 __attribute__((ext_vector_type(4)));

__device__ __forceinline__ ushort f2bf(float x) {
  unsigned u = __float_as_uint(x);
  u = (u + 0x7fffu + ((u >> 16) & 1u)) >> 16;   // RNE to bf16
  return (ushort)u;
}

// ---- prep: [D,M] fp32 -> [M,128] bf16 (pre-scaled); optionally fused argmax labels ----
__global__ void transpose_cvt_kernel(const float* __restrict__ X, ushort* __restrict__ Y,
                                     int M, float scale,
                                     const float* __restrict__ npl, int* __restrict__ nlab) {
  __shared__ float T[64][129];
  const int b = blockIdx.y;
  const int nbase = blockIdx.x * 64;
  const float* Xb = X + (size_t)b * D_ * M;
  ushort* Yb = Y + (size_t)b * M * D_;
  const int tid = threadIdx.x;
  const int nl = tid & 63;
  const int dw = tid >> 6;
#pragma unroll
  for (int i = 0; i < 32; ++i) {
    int d = i * 4 + dw;
    int gn = nbase + nl; if (gn >= M) gn = M - 1;
    T[nl][d] = Xb[(size_t)d * M + gn];
  }
  __syncthreads();
  const int d0 = (tid & 31) * 4;
#pragma unroll
  for (int i = 0; i < 8; ++i) {
    int n = i * 8 + (tid >> 5);
    int gn = nbase + n;
    if (gn < M) {
      ushort4 u;
      u.x = f2bf(T[n][d0 + 0] * scale);
      u.y = f2bf(T[n][d0 + 1] * scale);
      u.z = f2bf(T[n][d0 + 2] * scale);
      u.w = f2bf(T[n][d0 + 3] * scale);
      *(ushort4*)(Yb + (size_t)gn * D_ + d0) = u;
    }
  }
  // fused per-column argmax over classes (negatives path)
  if (nlab != nullptr && tid < 64) {
    int gn = nbase + tid;
    if (gn < M) {
      const float* base = npl + (size_t)b * C_ * M + gn;
      float best = base[0]; int bi = 0;
#pragma unroll
      for (int c = 1; c < C_; ++c) {
        float v = base[(size_t)c * M];
        if (v > best) { best = v; bi = c; }
      }
      nlab[b * M + gn] = bi;
    }
  }
}

// ---- prep: labels1, mask1 (argmax of 0/1 combo = first true else 0), pos1; zero neg_logits ----
__global__ void anchor_kernel(const float* __restrict__ pl1, const float* __restrict__ pl2,
                              const float* __restrict__ f1, const float* __restrict__ f2,
                              int* __restrict__ lab1, float* __restrict__ mask1,
                              float* __restrict__ pos1, float* __restrict__ neg_logits) {
  int b = blockIdx.y;
  int p = blockIdx.x * 256 + threadIdx.x;
  if (p >= P_) return;
  const float* a1 = pl1 + (size_t)b * C_ * P_ + p;
  const float* a2 = pl2 + (size_t)b * C_ * P_ + p;
  float best = a1[0]; int bi = 0;
  int mfirst = ((a1[0] < a2[0]) && (a2[0] > 0.75f)) ? 0 : -1;
#pragma unroll
  for (int c = 1; c < C_; ++c) {
    float v1 = a1[(size_t)c * P_], v2 = a2[(size_t)c * P_];
    if (v1 > best) { best = v1; bi = c; }
    if (mfirst < 0 && (v1 < v2) && (v2 > 0.75f)) mfirst = c;
  }
  lab1[b * P_ + p] = bi;
  mask1[b * P_ + p] = (mfirst < 0) ? 0.0f : (float)mfirst;
  neg_logits[b * P_ + p] = 0.0f;
  const float* g1 = f1 + (size_t)b * D_ * P_ + p;
  const float* g2 = f2 + (size_t)b * D_ * P_ + p;
  float s = 0.f;
#pragma unroll 8
  for (int d = 0; d < D_; ++d) s += g1[(size_t)d * P_] * g2[(size_t)d * P_];
  pos1[b * P_ + p] = s * 10.0f;   // /TEMP
}

// ---- fused GEMM + exp + mask + row-sum ----
// grid (PT, NSPLIT, NB), block 256. LDS: 1 x 128x128 bf16 (XOR-swizzled) = 32 KiB.
// A tile (read once per block) is loaded straight into register fragments.
__global__ __launch_bounds__(256, 4) void gemm_kernel(
    const ushort* __restrict__ At, const ushort* __restrict__ Bt,
    const int* __restrict__ lab1g, const int* __restrict__ nlabg,
    float* __restrict__ neg_logits) {
  __shared__ __attribute__((aligned(16))) ushort Bs[128 * 128];
  const int tid = threadIdx.x;
  const int b = blockIdx.z;
  const int ptile = blockIdx.x;
  const int wid = tid >> 6, lane = tid & 63;
  const int quad = lane >> 4, lm = lane & 15;
  const int qr = wid & 1, qc = wid >> 1;
  const ushort* Atb = At + (size_t)b * P_ * D_;
  const ushort* Btb = Bt + (size_t)b * N_ * D_;
  const int* lab1 = lab1g + b * P_;
  const int* nlab = nlabg + b * N_;

  // A fragments straight from global (each block reads its A tile exactly once)
  bf16x8 af[4][4];
#pragma unroll
  for (int r = 0; r < 4; ++r) {
    int p = ptile * 128 + qr * 64 + r * 16 + lm;
    if (p > P_ - 1) p = P_ - 1;
#pragma unroll
    for (int k0 = 0; k0 < 4; ++k0)
      af[r][k0] = *(const bf16x8*)(Atb + (size_t)p * D_ + (k0 * 4 + quad) * 8);
  }

  // labels of my 16 output rows
  int labp[16];
#pragma unroll
  for (int r = 0; r < 4; ++r)
#pragma unroll
    for (int g = 0; g < 4; ++g) {
      int p = ptile * 128 + qr * 64 + r * 16 + quad * 4 + g;
      labp[r * 4 + g] = lab1[p > P_ - 1 ? P_ - 1 : p];
    }

  float rsum[16];
#pragma unroll
  for (int i = 0; i < 16; ++i) rsum[i] = 0.f;

  const int c0 = (blockIdx.y * TOTCH) / NSPLIT;
  const int c1 = ((blockIdx.y + 1) * TOTCH) / NSPLIT;

  for (int j = c0; j < c1; ++j) {
    const int nbase = j * 128;
    __syncthreads();
#pragma unroll
    for (int i = 0; i < 8; ++i) {
      int cid = tid + i * 256;
      int row = cid >> 4, cc = cid & 15;
      uint4 v = *(const uint4*)(Btb + (size_t)(nbase + row) * D_ + cc * 8);
      *(uint4*)(&Bs[row * 128 + (cc ^ (row & 7)) * 8]) = v;
    }
    __syncthreads();

#pragma unroll
    for (int c = 0; c < 4; ++c) {
      const int row = qc * 64 + c * 16 + lm;
      f32x4 acc[4];
#pragma unroll
      for (int r = 0; r < 4; ++r)
#pragma unroll
        for (int g = 0; g < 4; ++g) acc[r][g] = 0.f;
#pragma unroll
      for (int k0 = 0; k0 < 4; ++k0) {
        int ch = (k0 * 4 + quad) ^ (row & 7);
        bf16x8 bf = *(const bf16x8*)(&Bs[row * 128 + ch * 8]);
#pragma unroll
        for (int r = 0; r < 4; ++r)
          acc[r] = __builtin_amdgcn_mfma_f32_16x16x32_bf16(af[r][k0], bf, acc[r], 0, 0, 0);
      }
      // epilogue for this column block: exp2 (A pre-scaled by 10*log2e) + label mask + row sums
      const int nl = nlab[nbase + row];
#pragma unroll
      for (int r = 0; r < 4; ++r)
#pragma unroll
        for (int g = 0; g < 4; ++g) {
          float e = __builtin_amdgcn_exp2f(acc[r][g]);
          rsum[r * 4 + g] += (labp[r * 4 + g] != nl) ? e : 0.f;
        }
    }
  }

  // reduce over the 16 lanes sharing a column group
#pragma unroll
  for (int i = 0; i < 16; ++i) {
    float v = rsum[i];
    v += __shfl_xor(v, 1);
    v += __shfl_xor(v, 2);
    v += __shfl_xor(v, 4);
    v += __shfl_xor(v, 8);
    rsum[i] = v;
  }
  if (lm == 0) {
#pragma unroll
    for (int r = 0; r < 4; ++r)
#pragma unroll
      for (int g = 0; g < 4; ++g) {
        int p = ptile * 128 + qr * 64 + r * 16 + quad * 4 + g;
        if (p < P_) atomicAdd(&neg_logits[b * P_ + p], rsum[r * 4 + g]);
      }
  }
}

// ---- finalize: weighted means, scalar out ----
__global__ void finalize_kernel(const float* __restrict__ neg_logits,
                                const float* __restrict__ pos1,
                                const float* __restrict__ mask1,
                                float* __restrict__ out) {
  double s1[2] = {0.0, 0.0}, s2[2] = {0.0, 0.0};
  for (int idx = threadIdx.x; idx < NB * P_; idx += 256) {
    int b = idx / P_;
    float ne = neg_logits[idx];
    float pe = __expf(pos1[idx]);
    float l = -logf(pe / (pe + ne + 1e-8f) + 1e-8f);
    float w = mask1[idx];
    s1[b] += (double)(w * l);
    s2[b] += (double)w;
  }
#pragma unroll
  for (int off = 32; off > 0; off >>= 1) {
    s1[0] += __shfl_down(s1[0], off);
    s2[0] += __shfl_down(s2[0], off);
    s1[1] += __shfl_down(s1[1], off);
    s2[1] += __shfl_down(s2[1], off);
  }
  __shared__ double sm[4][4];
  int wid = threadIdx.x >> 6, lane = threadIdx.x & 63;
  if (lane == 0) { sm[wid][0] = s1[0]; sm[wid][1] = s2[0]; sm[wid][2] = s1[1]; sm[wid][3] = s2[1]; }
  __syncthreads();
  if (threadIdx.x == 0) {
    double a = 0, bsum = 0, c = 0, d = 0;
    for (int w = 0; w < 4; ++w) { a += sm[w][0]; bsum += sm[w][1]; c += sm[w][2]; d += sm[w][3]; }
    out[0] = (float)(0.1 * (a / (bsum + 1e-8) + c / (d + 1e-8)));
  }
}

extern "C" void kernel_launch(void* const* d_in, const int* in_sizes, int n_in,
                              void* d_out, int out_size, void* d_ws, size_t ws_size,
                              hipStream_t stream) {
  const float* feats_view1 = (const float*)d_in[0];
  const float* pos_feats1  = (const float*)d_in[1];
  const float* pos_feats2  = (const float*)d_in[2];
  const float* pl1 = (const float*)d_in[3];
  const float* pl2 = (const float*)d_in[4];
  const float* npl = (const float*)d_in[5];

  char* ws = (char*)d_ws;
  ushort* Bt        = (ushort*)(ws + 0);          // 2*57600*128*2 = 29,491,200
  ushort* At        = (ushort*)(ws + 29491200);   //  1,843,200
  int*    nlab      = (int*)   (ws + 31334400);   //    460,800
  int*    lab1      = (int*)   (ws + 31795200);   //     28,800
  float*  mask1     = (float*) (ws + 31824000);   //     28,800
  float*  pos1      = (float*) (ws + 31852800);   //     28,800
  float*  neg_logits= (float*) (ws + 31881600);   //     28,800

  // B transpose + fused negative labels
  transpose_cvt_kernel<<<dim3(N_ / 64, NB), 256, 0, stream>>>(feats_view1, Bt, N_, 1.0f, npl, nlab);
  // A transpose, pre-scaled by (1/TEMP)*log2(e) so GEMM accumulator feeds exp2 directly
  transpose_cvt_kernel<<<dim3((P_ + 63) / 64, NB), 256, 0, stream>>>(pos_feats1, At, P_,
                                                                     14.4269504089f, nullptr, nullptr);
  anchor_kernel<<<dim3((P_ + 255) / 256, NB), 256, 0, stream>>>(pl1, pl2, pos_feats1, pos_feats2,
                                                                lab1, mask1, pos1, neg_logits);
  gemm_kernel<<<dim3(PT, NSPLIT, NB), 256, 0, stream>>>(At, Bt, lab1, nlab, neg_logits);
  finalize_kernel<<<1, 256, 0, stream>>>(neg_logits, pos1, mask1, (float*)d_out);
}

// Round 3
// 478.991 us; speedup vs baseline: 3.6646x; 3.6646x over previous
//
#include <hip/hip_runtime.h>
#include <string.h>

#define D_ 128
#define P_ 3600
#define N_ 57600
#define C_ 19
#define NB 2
#define NSPLIT 13
#define TOTCH 450    // 57600/128 column chunks
#define PT 29        // ceil(3600/128)

typedef short bf16x8 __attribute__((ext_vector_type(8)));
typedef float f32x4 __attribute__((ext_vector_type(4)));

__device__ __forceinline__ ushort f2bf(float x) {
  unsigned u = __float_as_uint(x);
  u = (u + 0x7fffu + ((u >> 16) & 1u)) >> 16;   // RNE to bf16
  return (ushort)u;
}

// ---- prep: [D,M] fp32 -> [M,128] bf16 (pre-scaled); optionally fused argmax labels ----
__global__ void transpose_cvt_kernel(const float* __restrict__ X, ushort* __restrict__ Y,
                                     int M, float scale,
                                     const float* __restrict__ npl, int* __restrict__ nlab) {
  __shared__ float T[64][129];
  const int b = blockIdx.y;
  const int nbase = blockIdx.x * 64;
  const float* Xb = X + (size_t)b * D_ * M;
  ushort* Yb = Y + (size_t)b * M * D_;
  const int tid = threadIdx.x;
  const int nl = tid & 63;
  const int dw = tid >> 6;
#pragma unroll
  for (int i = 0; i < 32; ++i) {
    int d = i * 4 + dw;
    int gn = nbase + nl; if (gn >= M) gn = M - 1;
    T[nl][d] = Xb[(size_t)d * M + gn];
  }
  __syncthreads();
  const int d0 = (tid & 31) * 4;
#pragma unroll
  for (int i = 0; i < 8; ++i) {
    int n = i * 8 + (tid >> 5);
    int gn = nbase + n;
    if (gn < M) {
      ushort4 u;
      u.x = f2bf(T[n][d0 + 0] * scale);
      u.y = f2bf(T[n][d0 + 1] * scale);
      u.z = f2bf(T[n][d0 + 2] * scale);
      u.w = f2bf(T[n][d0 + 3] * scale);
      *(ushort4*)(Yb + (size_t)gn * D_ + d0) = u;
    }
  }
  // fused per-column argmax over classes (negatives path)
  if (nlab != nullptr && tid < 64) {
    int gn = nbase + tid;
    if (gn < M) {
      const float* base = npl + (size_t)b * C_ * M + gn;
      float best = base[0]; int bi = 0;
#pragma unroll
      for (int c = 1; c < C_; ++c) {
        float v = base[(size_t)c * M];
        if (v > best) { best = v; bi = c; }
      }
      nlab[b * M + gn] = bi;
    }
  }
}

// ---- prep: labels1, mask1, pos1; zero neg_logits ----
__global__ void anchor_kernel(const float* __restrict__ pl1, const float* __restrict__ pl2,
                              const float* __restrict__ f1, const float* __restrict__ f2,
                              int* __restrict__ lab1, float* __restrict__ mask1,
                              float* __restrict__ pos1, float* __restrict__ neg_logits) {
  int b = blockIdx.y;
  int p = blockIdx.x * 256 + threadIdx.x;
  if (p >= P_) return;
  const float* a1 = pl1 + (size_t)b * C_ * P_ + p;
  const float* a2 = pl2 + (size_t)b * C_ * P_ + p;
  float best = a1[0]; int bi = 0;
  int mfirst = ((a1[0] < a2[0]) && (a2[0] > 0.75f)) ? 0 : -1;
#pragma unroll
  for (int c = 1; c < C_; ++c) {
    float v1 = a1[(size_t)c * P_], v2 = a2[(size_t)c * P_];
    if (v1 > best) { best = v1; bi = c; }
    if (mfirst < 0 && (v1 < v2) && (v2 > 0.75f)) mfirst = c;
  }
  lab1[b * P_ + p] = bi;
  mask1[b * P_ + p] = (mfirst < 0) ? 0.0f : (float)mfirst;
  neg_logits[b * P_ + p] = 0.0f;
  const float* g1 = f1 + (size_t)b * D_ * P_ + p;
  const float* g2 = f2 + (size_t)b * D_ * P_ + p;
  float s = 0.f;
#pragma unroll 8
  for (int d = 0; d < D_; ++d) s += g1[(size_t)d * P_] * g2[(size_t)d * P_];
  pos1[b * P_ + p] = s * 10.0f;   // /TEMP
}

// ---- fused GEMM + exp + mask + row-sum ----
// grid (PT, NSPLIT, NB), block 256. LDS: 1 x 128x128 bf16 (XOR-swizzled) = 32 KiB.
// A tile held in register fragments; __launch_bounds__(256,3) -> VGPR cap 170
// (need ~150 live; the (256,4) cap of 128 forced spills last round: 342 MB scratch writes).
__global__ __launch_bounds__(256, 3) void gemm_kernel(
    const ushort* __restrict__ At, const ushort* __restrict__ Bt,
    const int* __restrict__ lab1g, const int* __restrict__ nlabg,
    float* __restrict__ neg_logits) {
  __shared__ __attribute__((aligned(16))) ushort Bs[128 * 128];
  const int tid = threadIdx.x;
  const int b = blockIdx.z;
  const int ptile = blockIdx.x;
  const int wid = tid >> 6, lane = tid & 63;
  const int quad = lane >> 4, lm = lane & 15;
  const int qr = wid & 1, qc = wid >> 1;
  const ushort* Atb = At + (size_t)b * P_ * D_;
  const ushort* Btb = Bt + (size_t)b * N_ * D_;
  const int* lab1 = lab1g + b * P_;
  const int* nlab = nlabg + b * N_;

  // A fragments straight from global (each block reads its A tile exactly once)
  bf16x8 af[4][4];
#pragma unroll
  for (int r = 0; r < 4; ++r) {
    int p = ptile * 128 + qr * 64 + r * 16 + lm;
    if (p > P_ - 1) p = P_ - 1;
#pragma unroll
    for (int k0 = 0; k0 < 4; ++k0)
      af[r][k0] = *(const bf16x8*)(Atb + (size_t)p * D_ + (k0 * 4 + quad) * 8);
  }

  // labels of my 16 output rows
  int labp[16];
#pragma unroll
  for (int r = 0; r < 4; ++r)
#pragma unroll
    for (int g = 0; g < 4; ++g) {
      int p = ptile * 128 + qr * 64 + r * 16 + quad * 4 + g;
      labp[r * 4 + g] = lab1[p > P_ - 1 ? P_ - 1 : p];
    }

  float rsum[16];
#pragma unroll
  for (int i = 0; i < 16; ++i) rsum[i] = 0.f;

  const int c0 = (blockIdx.y * TOTCH) / NSPLIT;
  const int c1 = ((blockIdx.y + 1) * TOTCH) / NSPLIT;

  for (int j = c0; j < c1; ++j) {
    const int nbase = j * 128;
    __syncthreads();
#pragma unroll
    for (int i = 0; i < 8; ++i) {
      int cid = tid + i * 256;
      int row = cid >> 4, cc = cid & 15;
      uint4 v = *(const uint4*)(Btb + (size_t)(nbase + row) * D_ + cc * 8);
      *(uint4*)(&Bs[row * 128 + (cc ^ (row & 7)) * 8]) = v;
    }
    __syncthreads();

#pragma unroll
    for (int c = 0; c < 4; ++c) {
      const int row = qc * 64 + c * 16 + lm;
      f32x4 acc[4];
#pragma unroll
      for (int r = 0; r < 4; ++r)
#pragma unroll
        for (int g = 0; g < 4; ++g) acc[r][g] = 0.f;
#pragma unroll
      for (int k0 = 0; k0 < 4; ++k0) {
        int ch = (k0 * 4 + quad) ^ (row & 7);
        bf16x8 bf = *(const bf16x8*)(&Bs[row * 128 + ch * 8]);
#pragma unroll
        for (int r = 0; r < 4; ++r)
          acc[r] = __builtin_amdgcn_mfma_f32_16x16x32_bf16(af[r][k0], bf, acc[r], 0, 0, 0);
      }
      // epilogue: exp2 (A pre-scaled by 10*log2e) + label mask + row sums
      const int nl = nlab[nbase + row];
#pragma unroll
      for (int r = 0; r < 4; ++r)
#pragma unroll
        for (int g = 0; g < 4; ++g) {
          float e = __builtin_amdgcn_exp2f(acc[r][g]);
          rsum[r * 4 + g] += (labp[r * 4 + g] != nl) ? e : 0.f;
        }
    }
  }

  // reduce over the 16 lanes sharing a column group
#pragma unroll
  for (int i = 0; i < 16; ++i) {
    float v = rsum[i];
    v += __shfl_xor(v, 1);
    v += __shfl_xor(v, 2);
    v += __shfl_xor(v, 4);
    v += __shfl_xor(v, 8);
    rsum[i] = v;
  }
  if (lm == 0) {
#pragma unroll
    for (int r = 0; r < 4; ++r)
#pragma unroll
      for (int g = 0; g < 4; ++g) {
        int p = ptile * 128 + qr * 64 + r * 16 + quad * 4 + g;
        if (p < P_) atomicAdd(&neg_logits[b * P_ + p], rsum[r * 4 + g]);
      }
  }
}

// ---- finalize: weighted means, scalar out ----
__global__ void finalize_kernel(const float* __restrict__ neg_logits,
                                const float* __restrict__ pos1,
                                const float* __restrict__ mask1,
                                float* __restrict__ out) {
  double s1[2] = {0.0, 0.0}, s2[2] = {0.0, 0.0};
  for (int idx = threadIdx.x; idx < NB * P_; idx += 256) {
    int b = idx / P_;
    float ne = neg_logits[idx];
    float pe = __expf(pos1[idx]);
    float l = -logf(pe / (pe + ne + 1e-8f) + 1e-8f);
    float w = mask1[idx];
    s1[b] += (double)(w * l);
    s2[b] += (double)w;
  }
#pragma unroll
  for (int off = 32; off > 0; off >>= 1) {
    s1[0] += __shfl_down(s1[0], off);
    s2[0] += __shfl_down(s2[0], off);
    s1[1] += __shfl_down(s1[1], off);
    s2[1] += __shfl_down(s2[1], off);
  }
  __shared__ double sm[4][4];
  int wid = threadIdx.x >> 6, lane = threadIdx.x & 63;
  if (lane == 0) { sm[wid][0] = s1[0]; sm[wid][1] = s2[0]; sm[wid][2] = s1[1]; sm[wid][3] = s2[1]; }
  __syncthreads();
  if (threadIdx.x == 0) {
    double a = 0, bsum = 0, c = 0, d = 0;
    for (int w = 0; w < 4; ++w) { a += sm[w][0]; bsum += sm[w][1]; c += sm[w][2]; d += sm[w][3]; }
    out[0] = (float)(0.1 * (a / (bsum + 1e-8) + c / (d + 1e-8)));
  }
}

extern "C" void kernel_launch(void* const* d_in, const int* in_sizes, int n_in,
                              void* d_out, int out_size, void* d_ws, size_t ws_size,
                              hipStream_t stream) {
  const float* feats_view1 = (const float*)d_in[0];
  const float* pos_feats1  = (const float*)d_in[1];
  const float* pos_feats2  = (const float*)d_in[2];
  const float* pl1 = (const float*)d_in[3];
  const float* pl2 = (const float*)d_in[4];
  const float* npl = (const float*)d_in[5];

  char* ws = (char*)d_ws;
  ushort* Bt        = (ushort*)(ws + 0);          // 2*57600*128*2 = 29,491,200
  ushort* At        = (ushort*)(ws + 29491200);   //  1,843,200
  int*    nlab      = (int*)   (ws + 31334400);   //    460,800
  int*    lab1      = (int*)   (ws + 31795200);   //     28,800
  float*  mask1     = (float*) (ws + 31824000);   //     28,800
  float*  pos1      = (float*) (ws + 31852800);   //     28,800
  float*  neg_logits= (float*) (ws + 31881600);   //     28,800

  // B transpose + fused negative labels
  transpose_cvt_kernel<<<dim3(N_ / 64, NB), 256, 0, stream>>>(feats_view1, Bt, N_, 1.0f, npl, nlab);
  // A transpose, pre-scaled by (1/TEMP)*log2(e) so GEMM accumulator feeds exp2 directly
  transpose_cvt_kernel<<<dim3((P_ + 63) / 64, NB), 256, 0, stream>>>(pos_feats1, At, P_,
                                                                     14.4269504089f, nullptr, nullptr);
  anchor_kernel<<<dim3((P_ + 255) / 256, NB), 256, 0, stream>>>(pl1, pl2, pos_feats1, pos_feats2,
                                                                lab1, mask1, pos1, neg_logits);
  gemm_kernel<<<dim3(PT, NSPLIT, NB), 256, 0, stream>>>(At, Bt, lab1, nlab, neg_logits);
  finalize_kernel<<<1, 256, 0, stream>>>(neg_logits, pos1, mask1, (float*)d_out);
}

// Round 4
// 453.925 us; speedup vs baseline: 3.8669x; 1.0552x over previous
//
#include <hip/hip_runtime.h>
#include <string.h>

#define D_ 128
#define P_ 3600
#define N_ 57600
#define C_ 19
#define NB 2
#define NSPLIT 13
#define TOTCH 450    // 57600/128 column chunks
#define PT 29        // ceil(3600/128)

typedef short bf16x8 __attribute__((ext_vector_type(8)));
typedef float f32x4 __attribute__((ext_vector_type(4)));

__device__ __forceinline__ ushort f2bf(float x) {
  unsigned u = __float_as_uint(x);
  u = (u + 0x7fffu + ((u >> 16) & 1u)) >> 16;   // RNE to bf16
  return (ushort)u;
}

// ---- prep: [D,M] fp32 -> [M,128] bf16 (pre-scaled); B path fuses negative-label argmax ----
// grid.x = 900 (B tiles) + 57 (A tiles); grid.y = NB
__global__ void transpose_cvt_kernel(const float* __restrict__ XB, ushort* __restrict__ YB,
                                     const float* __restrict__ XA, ushort* __restrict__ YA,
                                     const float* __restrict__ npl, int* __restrict__ nlab) {
  __shared__ float T[64][129];
  const int b = blockIdx.y;
  const bool isB = blockIdx.x < (N_ / 64);
  const int M = isB ? N_ : P_;
  const float scale = isB ? 1.0f : 14.4269504089f;  // A pre-scaled by (1/TEMP)*log2(e)
  const int nbase = (isB ? blockIdx.x : (blockIdx.x - N_ / 64)) * 64;
  const float* Xb = (isB ? XB : XA) + (size_t)b * D_ * M;
  ushort* Yb = (isB ? YB : YA) + (size_t)b * M * D_;
  const int tid = threadIdx.x;
  const int nl = tid & 63;
  const int dw = tid >> 6;
#pragma unroll
  for (int i = 0; i < 32; ++i) {
    int d = i * 4 + dw;
    int gn = nbase + nl; if (gn >= M) gn = M - 1;
    T[nl][d] = Xb[(size_t)d * M + gn];
  }
  __syncthreads();
  const int d0 = (tid & 31) * 4;
#pragma unroll
  for (int i = 0; i < 8; ++i) {
    int n = i * 8 + (tid >> 5);
    int gn = nbase + n;
    if (gn < M) {
      ushort4 u;
      u.x = f2bf(T[n][d0 + 0] * scale);
      u.y = f2bf(T[n][d0 + 1] * scale);
      u.z = f2bf(T[n][d0 + 2] * scale);
      u.w = f2bf(T[n][d0 + 3] * scale);
      *(ushort4*)(Yb + (size_t)gn * D_ + d0) = u;
    }
  }
  // fused per-column argmax over classes (negatives path)
  if (isB && tid < 64) {
    int gn = nbase + tid;
    const float* base = npl + (size_t)b * C_ * N_ + gn;
    float best = base[0]; int bi = 0;
#pragma unroll
    for (int c = 1; c < C_; ++c) {
      float v = base[(size_t)c * N_];
      if (v > best) { best = v; bi = c; }
    }
    nlab[b * N_ + gn] = bi;
  }
}

// ---- prep: labels1, mask1, pos1; zero neg_logits ----
__global__ void anchor_kernel(const float* __restrict__ pl1, const float* __restrict__ pl2,
                              const float* __restrict__ f1, const float* __restrict__ f2,
                              int* __restrict__ lab1, float* __restrict__ mask1,
                              float* __restrict__ pos1, float* __restrict__ neg_logits) {
  int b = blockIdx.y;
  int p = blockIdx.x * 256 + threadIdx.x;
  if (p >= P_) return;
  const float* a1 = pl1 + (size_t)b * C_ * P_ + p;
  const float* a2 = pl2 + (size_t)b * C_ * P_ + p;
  float best = a1[0]; int bi = 0;
  int mfirst = ((a1[0] < a2[0]) && (a2[0] > 0.75f)) ? 0 : -1;
#pragma unroll
  for (int c = 1; c < C_; ++c) {
    float v1 = a1[(size_t)c * P_], v2 = a2[(size_t)c * P_];
    if (v1 > best) { best = v1; bi = c; }
    if (mfirst < 0 && (v1 < v2) && (v2 > 0.75f)) mfirst = c;
  }
  lab1[b * P_ + p] = bi;
  mask1[b * P_ + p] = (mfirst < 0) ? 0.0f : (float)mfirst;
  neg_logits[b * P_ + p] = 0.0f;
  const float* g1 = f1 + (size_t)b * D_ * P_ + p;
  const float* g2 = f2 + (size_t)b * D_ * P_ + p;
  float s = 0.f;
#pragma unroll 8
  for (int d = 0; d < D_; ++d) s += g1[(size_t)d * P_] * g2[(size_t)d * P_];
  pos1[b * P_ + p] = s * 10.0f;   // /TEMP
}

// ---- fused GEMM + exp + mask + row-sum ----
// grid (PT, NSPLIT, NB), block 256. ONE 32 KiB LDS buffer (XOR-swizzled), used first
// for the A tile (read into register fragments via ds_read -> NOT rematerializable,
// unlike the global loads that R3's allocator sank back into the loop), then reused
// for B chunks. __launch_bounds__(256,3): VGPR cap 170 fits ~140 live regs, 3 blocks/CU.
__global__ __launch_bounds__(256, 3) void gemm_kernel(
    const ushort* __restrict__ At, const ushort* __restrict__ Bt,
    const int* __restrict__ lab1g, const int* __restrict__ nlabg,
    float* __restrict__ neg_logits) {
  __shared__ __attribute__((aligned(16))) ushort Bs[128 * 128];
  const int tid = threadIdx.x;
  const int b = blockIdx.z;
  const int ptile = blockIdx.x;
  const int wid = tid >> 6, lane = tid & 63;
  const int quad = lane >> 4, lm = lane & 15;
  const int qr = wid & 1, qc = wid >> 1;
  const ushort* Atb = At + (size_t)b * P_ * D_;
  const ushort* Btb = Bt + (size_t)b * N_ * D_;
  const int* lab1 = lab1g + b * P_;
  const int* nlab = nlabg + b * N_;

  // ---- stage A tile into LDS (rows clamped for the partial last tile) ----
#pragma unroll
  for (int i = 0; i < 8; ++i) {
    int cid = tid + i * 256;
    int row = cid >> 4, cc = cid & 15;
    int p = ptile * 128 + row; if (p > P_ - 1) p = P_ - 1;
    uint4 v = *(const uint4*)(Atb + (size_t)p * D_ + cc * 8);
    *(uint4*)(&Bs[row * 128 + (cc ^ (row & 7)) * 8]) = v;
  }
  __syncthreads();

  // ---- A fragments LDS -> registers (held for the whole kernel) ----
  bf16x8 af[4][4];
#pragma unroll
  for (int r = 0; r < 4; ++r) {
    int row = qr * 64 + r * 16 + lm;
#pragma unroll
    for (int k0 = 0; k0 < 4; ++k0) {
      int ch = (k0 * 4 + quad) ^ (row & 7);
      af[r][k0] = *(const bf16x8*)(&Bs[row * 128 + ch * 8]);
    }
  }

  // labels of my 16 output rows
  int labp[16];
#pragma unroll
  for (int r = 0; r < 4; ++r)
#pragma unroll
    for (int g = 0; g < 4; ++g) {
      int p = ptile * 128 + qr * 64 + r * 16 + quad * 4 + g;
      labp[r * 4 + g] = lab1[p > P_ - 1 ? P_ - 1 : p];
    }

  float rsum[16];
#pragma unroll
  for (int i = 0; i < 16; ++i) rsum[i] = 0.f;
  const f32x4 zero4 = {0.f, 0.f, 0.f, 0.f};   // persistent C operand for first MFMA of each block

  const int c0 = (blockIdx.y * TOTCH) / NSPLIT;
  const int c1 = ((blockIdx.y + 1) * TOTCH) / NSPLIT;

  for (int j = c0; j < c1; ++j) {
    const int nbase = j * 128;
    __syncthreads();   // also protects the af ds_reads on the first iteration
#pragma unroll
    for (int i = 0; i < 8; ++i) {
      int cid = tid + i * 256;
      int row = cid >> 4, cc = cid & 15;
      uint4 v = *(const uint4*)(Btb + (size_t)(nbase + row) * D_ + cc * 8);
      *(uint4*)(&Bs[row * 128 + (cc ^ (row & 7)) * 8]) = v;
    }
    __syncthreads();

#pragma unroll
    for (int c = 0; c < 4; ++c) {
      const int row = qc * 64 + c * 16 + lm;
      const int nl = nlab[nbase + row];
      f32x4 acc[4];
      {
        int ch = quad ^ (row & 7);
        bf16x8 bf = *(const bf16x8*)(&Bs[row * 128 + ch * 8]);
#pragma unroll
        for (int r = 0; r < 4; ++r)
          acc[r] = __builtin_amdgcn_mfma_f32_16x16x32_bf16(af[r][0], bf, zero4, 0, 0, 0);
      }
#pragma unroll
      for (int k0 = 1; k0 < 4; ++k0) {
        int ch = (k0 * 4 + quad) ^ (row & 7);
        bf16x8 bf = *(const bf16x8*)(&Bs[row * 128 + ch * 8]);
#pragma unroll
        for (int r = 0; r < 4; ++r)
          acc[r] = __builtin_amdgcn_mfma_f32_16x16x32_bf16(af[r][k0], bf, acc[r], 0, 0, 0);
      }
      // epilogue: exp2 (A pre-scaled by 10*log2e) + label mask + row sums
#pragma unroll
      for (int r = 0; r < 4; ++r)
#pragma unroll
        for (int g = 0; g < 4; ++g) {
          float e = __builtin_amdgcn_exp2f(acc[r][g]);
          rsum[r * 4 + g] += (labp[r * 4 + g] != nl) ? e : 0.f;
        }
    }
  }

  // reduce over the 16 lanes sharing a column group
#pragma unroll
  for (int i = 0; i < 16; ++i) {
    float v = rsum[i];
    v += __shfl_xor(v, 1);
    v += __shfl_xor(v, 2);
    v += __shfl_xor(v, 4);
    v += __shfl_xor(v, 8);
    rsum[i] = v;
  }
  if (lm == 0) {
#pragma unroll
    for (int r = 0; r < 4; ++r)
#pragma unroll
      for (int g = 0; g < 4; ++g) {
        int p = ptile * 128 + qr * 64 + r * 16 + quad * 4 + g;
        if (p < P_) atomicAdd(&neg_logits[b * P_ + p], rsum[r * 4 + g]);
      }
  }
}

// ---- finalize: weighted means, scalar out ----
__global__ void finalize_kernel(const float* __restrict__ neg_logits,
                                const float* __restrict__ pos1,
                                const float* __restrict__ mask1,
                                float* __restrict__ out) {
  double s1[2] = {0.0, 0.0}, s2[2] = {0.0, 0.0};
  for (int idx = threadIdx.x; idx < NB * P_; idx += 256) {
    int b = idx / P_;
    float ne = neg_logits[idx];
    float pe = __expf(pos1[idx]);
    float l = -logf(pe / (pe + ne + 1e-8f) + 1e-8f);
    float w = mask1[idx];
    s1[b] += (double)(w * l);
    s2[b] += (double)w;
  }
#pragma unroll
  for (int off = 32; off > 0; off >>= 1) {
    s1[0] += __shfl_down(s1[0], off);
    s2[0] += __shfl_down(s2[0], off);
    s1[1] += __shfl_down(s1[1], off);
    s2[1] += __shfl_down(s2[1], off);
  }
  __shared__ double sm[4][4];
  int wid = threadIdx.x >> 6, lane = threadIdx.x & 63;
  if (lane == 0) { sm[wid][0] = s1[0]; sm[wid][1] = s2[0]; sm[wid][2] = s1[1]; sm[wid][3] = s2[1]; }
  __syncthreads();
  if (threadIdx.x == 0) {
    double a = 0, bsum = 0, c = 0, d = 0;
    for (int w = 0; w < 4; ++w) { a += sm[w][0]; bsum += sm[w][1]; c += sm[w][2]; d += sm[w][3]; }
    out[0] = (float)(0.1 * (a / (bsum + 1e-8) + c / (d + 1e-8)));
  }
}

extern "C" void kernel_launch(void* const* d_in, const int* in_sizes, int n_in,
                              void* d_out, int out_size, void* d_ws, size_t ws_size,
                              hipStream_t stream) {
  const float* feats_view1 = (const float*)d_in[0];
  const float* pos_feats1  = (const float*)d_in[1];
  const float* pos_feats2  = (const float*)d_in[2];
  const float* pl1 = (const float*)d_in[3];
  const float* pl2 = (const float*)d_in[4];
  const float* npl = (const float*)d_in[5];

  char* ws = (char*)d_ws;
  ushort* Bt        = (ushort*)(ws + 0);          // 2*57600*128*2 = 29,491,200
  ushort* At        = (ushort*)(ws + 29491200);   //  1,843,200
  int*    nlab      = (int*)   (ws + 31334400);   //    460,800
  int*    lab1      = (int*)   (ws + 31795200);   //     28,800
  float*  mask1     = (float*) (ws + 31824000);   //     28,800
  float*  pos1      = (float*) (ws + 31852800);   //     28,800
  float*  neg_logits= (float*) (ws + 31881600);   //     28,800

  // fused A+B transpose (+ negative labels on the B path)
  transpose_cvt_kernel<<<dim3(N_ / 64 + 57, NB), 256, 0, stream>>>(feats_view1, Bt,
                                                                   pos_feats1, At, npl, nlab);
  anchor_kernel<<<dim3((P_ + 255) / 256, NB), 256, 0, stream>>>(pl1, pl2, pos_feats1, pos_feats2,
                                                                lab1, mask1, pos1, neg_logits);
  gemm_kernel<<<dim3(PT, NSPLIT, NB), 256, 0, stream>>>(At, Bt, lab1, nlab, neg_logits);
  finalize_kernel<<<1, 256, 0, stream>>>(neg_logits, pos1, mask1, (float*)d_out);
}

// Round 5
// 404.177 us; speedup vs baseline: 4.3429x; 1.1231x over previous
//
#include <hip/hip_runtime.h>
#include <string.h>

#define D_ 128
#define P_ 3600
#define N_ 57600
#define C_ 19
#define NB 2
#define NSPLIT 30
#define TOTCH 450    // 57600/128 column chunks; 15 chunks per block
#define PT 29        // ceil(3600/128)

typedef short bf16x8 __attribute__((ext_vector_type(8)));
typedef float f32x4 __attribute__((ext_vector_type(4)));

__device__ __forceinline__ ushort f2bf(float x) {
  unsigned u = __float_as_uint(x);
  u = (u + 0x7fffu + ((u >> 16) & 1u)) >> 16;   // RNE to bf16
  return (ushort)u;
}

// async global->LDS DMA, 16B per lane; LDS dest = wave-uniform base + lane*16
__device__ __forceinline__ void gload_lds16(const void* g, void* l) {
  __builtin_amdgcn_global_load_lds(
      (const __attribute__((address_space(1))) unsigned int*)g,
      (__attribute__((address_space(3))) unsigned int*)l, 16, 0, 0);
}

// ---- prep: fused B transpose (+neg labels), A transpose, and anchor work ----
// grid.x = 900 (B tiles) + 57 (A tiles) + 15 (anchor blocks); grid.y = NB
__global__ void prep_kernel(const float* __restrict__ XB, ushort* __restrict__ YB,
                            const float* __restrict__ XA, ushort* __restrict__ YA,
                            const float* __restrict__ npl, int* __restrict__ nlab,
                            const float* __restrict__ pl1, const float* __restrict__ pl2,
                            const float* __restrict__ f2,
                            int* __restrict__ lab1, float* __restrict__ mask1,
                            float* __restrict__ pos1, float* __restrict__ neg_logits) {
  __shared__ float T[64][129];
  const int b = blockIdx.y;
  const int tid = threadIdx.x;

  if (blockIdx.x >= N_ / 64 + 57) {
    // ---- anchor path: labels1, mask1, pos1, zero neg_logits ----
    int p = (blockIdx.x - (N_ / 64 + 57)) * 256 + tid;
    if (p >= P_) return;
    const float* a1 = pl1 + (size_t)b * C_ * P_ + p;
    const float* a2 = pl2 + (size_t)b * C_ * P_ + p;
    float best = a1[0]; int bi = 0;
    int mfirst = ((a1[0] < a2[0]) && (a2[0] > 0.75f)) ? 0 : -1;
#pragma unroll
    for (int c = 1; c < C_; ++c) {
      float v1 = a1[(size_t)c * P_], v2 = a2[(size_t)c * P_];
      if (v1 > best) { best = v1; bi = c; }
      if (mfirst < 0 && (v1 < v2) && (v2 > 0.75f)) mfirst = c;
    }
    lab1[b * P_ + p] = bi;
    mask1[b * P_ + p] = (mfirst < 0) ? 0.0f : (float)mfirst;
    neg_logits[b * P_ + p] = 0.0f;
    const float* g1 = XA + (size_t)b * D_ * P_ + p;
    const float* g2 = f2 + (size_t)b * D_ * P_ + p;
    float s = 0.f;
#pragma unroll 8
    for (int d = 0; d < D_; ++d) s += g1[(size_t)d * P_] * g2[(size_t)d * P_];
    pos1[b * P_ + p] = s * 10.0f;   // /TEMP
    return;
  }

  // ---- transpose path: [D,M] fp32 -> [M,128] bf16 (pre-scaled) ----
  const bool isB = blockIdx.x < (N_ / 64);
  const int M = isB ? N_ : P_;
  const float scale = isB ? 1.0f : 14.4269504089f;  // A pre-scaled by (1/TEMP)*log2(e)
  const int nbase = (isB ? blockIdx.x : (blockIdx.x - N_ / 64)) * 64;
  const float* Xb = (isB ? XB : XA) + (size_t)b * D_ * M;
  ushort* Yb = (isB ? YB : YA) + (size_t)b * M * D_;
  const int nl = tid & 63;
  const int dw = tid >> 6;
#pragma unroll
  for (int i = 0; i < 32; ++i) {
    int d = i * 4 + dw;
    int gn = nbase + nl; if (gn >= M) gn = M - 1;
    T[nl][d] = Xb[(size_t)d * M + gn];
  }
  __syncthreads();
  const int d0 = (tid & 31) * 4;
#pragma unroll
  for (int i = 0; i < 8; ++i) {
    int n = i * 8 + (tid >> 5);
    int gn = nbase + n;
    if (gn < M) {
      ushort4 u;
      u.x = f2bf(T[n][d0 + 0] * scale);
      u.y = f2bf(T[n][d0 + 1] * scale);
      u.z = f2bf(T[n][d0 + 2] * scale);
      u.w = f2bf(T[n][d0 + 3] * scale);
      *(ushort4*)(Yb + (size_t)gn * D_ + d0) = u;
    }
  }
  if (isB && tid < 64) {
    int gn = nbase + tid;
    const float* base = npl + (size_t)b * C_ * N_ + gn;
    float best = base[0]; int bi = 0;
#pragma unroll
    for (int c = 1; c < C_; ++c) {
      float v = base[(size_t)c * N_];
      if (v > best) { best = v; bi = c; }
    }
    nlab[b * N_ + gn] = bi;
  }
}

// ---- fused GEMM + exp + mask + row-sum ----
// grid (PT, NSPLIT, NB), block 256. ONE 32 KiB LDS buffer reused for A then B chunks.
// Staging via global_load_lds (16B/lane DMA); the XOR bank-swizzle is applied on the
// GLOBAL source address (involutive), since the DMA's LDS side is uniform+lane*16.
// NSPLIT=30 -> 15 chunks/block, 1740 blocks in ~2.3 dispatch waves: short-lived,
// phase-locked blocks so same-y blocks share B chunks in L2 (R4's 34-chunk resident
// blocks drifted out of phase -> 918 MB FETCH, 0% L2 reuse).
__global__ __launch_bounds__(256, 3) void gemm_kernel(
    const ushort* __restrict__ At, const ushort* __restrict__ Bt,
    const int* __restrict__ lab1g, const int* __restrict__ nlabg,
    float* __restrict__ neg_logits) {
  __shared__ __attribute__((aligned(16))) ushort Bs[128 * 128];
  const int tid = threadIdx.x;
  const int b = blockIdx.z;
  const int ptile = blockIdx.x;
  const int wid = tid >> 6, lane = tid & 63;
  const int quad = lane >> 4, lm = lane & 15;
  const int qr = wid & 1, qc = wid >> 1;
  const ushort* Atb = At + (size_t)b * P_ * D_;
  const ushort* Btb = Bt + (size_t)b * N_ * D_;
  const int* lab1 = lab1g + b * P_;
  const int* nlab = nlabg + b * N_;

  const int row4 = wid * 4 + (lane >> 4);       // my row within each 16-row group
  const int cc = lane & 15;
  const int swz = cc ^ (row4 & 7);              // xor swizzle, loop-invariant (16 % 8 == 0)

  // ---- stage A tile into LDS via DMA (rows clamped for the partial last tile) ----
#pragma unroll
  for (int i = 0; i < 8; ++i) {
    int row = i * 16 + row4;
    int p = ptile * 128 + row; if (p > P_ - 1) p = P_ - 1;
    gload_lds16(Atb + (size_t)p * D_ + swz * 8, &Bs[(i * 16 + wid * 4) * 128]);
  }
  __syncthreads();

  // ---- A fragments LDS -> registers (held for the whole kernel) ----
  bf16x8 af[4][4];
#pragma unroll
  for (int r = 0; r < 4; ++r) {
    int row = qr * 64 + r * 16 + lm;
#pragma unroll
    for (int k0 = 0; k0 < 4; ++k0) {
      int ch = (k0 * 4 + quad) ^ (row & 7);
      af[r][k0] = *(const bf16x8*)(&Bs[row * 128 + ch * 8]);
    }
  }

  // labels of my 16 output rows
  int labp[16];
#pragma unroll
  for (int r = 0; r < 4; ++r)
#pragma unroll
    for (int g = 0; g < 4; ++g) {
      int p = ptile * 128 + qr * 64 + r * 16 + quad * 4 + g;
      labp[r * 4 + g] = lab1[p > P_ - 1 ? P_ - 1 : p];
    }

  float rsum[16];
#pragma unroll
  for (int i = 0; i < 16; ++i) rsum[i] = 0.f;
  const f32x4 zero4 = {0.f, 0.f, 0.f, 0.f};

  const int c0 = (blockIdx.y * TOTCH) / NSPLIT;
  const int c1 = ((blockIdx.y + 1) * TOTCH) / NSPLIT;

  for (int j = c0; j < c1; ++j) {
    const int nbase = j * 128;
    __syncthreads();   // af reads / previous chunk's ds_reads complete before DMA lands
    const ushort* src = Btb + (size_t)nbase * D_ + swz * 8 + (size_t)row4 * D_;
#pragma unroll
    for (int i = 0; i < 8; ++i)
      gload_lds16(src + (size_t)i * 16 * D_, &Bs[(i * 16 + wid * 4) * 128]);
    __syncthreads();

#pragma unroll
    for (int c = 0; c < 4; ++c) {
      const int row = qc * 64 + c * 16 + lm;
      const int nl = nlab[nbase + row];
      f32x4 acc[4];
      {
        int ch = quad ^ (row & 7);
        bf16x8 bf = *(const bf16x8*)(&Bs[row * 128 + ch * 8]);
#pragma unroll
        for (int r = 0; r < 4; ++r)
          acc[r] = __builtin_amdgcn_mfma_f32_16x16x32_bf16(af[r][0], bf, zero4, 0, 0, 0);
      }
#pragma unroll
      for (int k0 = 1; k0 < 4; ++k0) {
        int ch = (k0 * 4 + quad) ^ (row & 7);
        bf16x8 bf = *(const bf16x8*)(&Bs[row * 128 + ch * 8]);
#pragma unroll
        for (int r = 0; r < 4; ++r)
          acc[r] = __builtin_amdgcn_mfma_f32_16x16x32_bf16(af[r][k0], bf, acc[r], 0, 0, 0);
      }
      // epilogue: exp2 (A pre-scaled by 10*log2e) + label mask + row sums
#pragma unroll
      for (int r = 0; r < 4; ++r)
#pragma unroll
        for (int g = 0; g < 4; ++g) {
          float e = __builtin_amdgcn_exp2f(acc[r][g]);
          rsum[r * 4 + g] += (labp[r * 4 + g] != nl) ? e : 0.f;
        }
    }
  }

  // reduce over the 16 lanes sharing a column group
#pragma unroll
  for (int i = 0; i < 16; ++i) {
    float v = rsum[i];
    v += __shfl_xor(v, 1);
    v += __shfl_xor(v, 2);
    v += __shfl_xor(v, 4);
    v += __shfl_xor(v, 8);
    rsum[i] = v;
  }
  if (lm == 0) {
#pragma unroll
    for (int r = 0; r < 4; ++r)
#pragma unroll
      for (int g = 0; g < 4; ++g) {
        int p = ptile * 128 + qr * 64 + r * 16 + quad * 4 + g;
        if (p < P_) atomicAdd(&neg_logits[b * P_ + p], rsum[r * 4 + g]);
      }
  }
}

// ---- finalize: weighted means, scalar out ----
__global__ void finalize_kernel(const float* __restrict__ neg_logits,
                                const float* __restrict__ pos1,
                                const float* __restrict__ mask1,
                                float* __restrict__ out) {
  double s1[2] = {0.0, 0.0}, s2[2] = {0.0, 0.0};
  for (int idx = threadIdx.x; idx < NB * P_; idx += 256) {
    int b = idx / P_;
    float ne = neg_logits[idx];
    float pe = __expf(pos1[idx]);
    float l = -logf(pe / (pe + ne + 1e-8f) + 1e-8f);
    float w = mask1[idx];
    s1[b] += (double)(w * l);
    s2[b] += (double)w;
  }
#pragma unroll
  for (int off = 32; off > 0; off >>= 1) {
    s1[0] += __shfl_down(s1[0], off);
    s2[0] += __shfl_down(s2[0], off);
    s1[1] += __shfl_down(s1[1], off);
    s2[1] += __shfl_down(s2[1], off);
  }
  __shared__ double sm[4][4];
  int wid = threadIdx.x >> 6, lane = threadIdx.x & 63;
  if (lane == 0) { sm[wid][0] = s1[0]; sm[wid][1] = s2[0]; sm[wid][2] = s1[1]; sm[wid][3] = s2[1]; }
  __syncthreads();
  if (threadIdx.x == 0) {
    double a = 0, bsum = 0, c = 0, d = 0;
    for (int w = 0; w < 4; ++w) { a += sm[w][0]; bsum += sm[w][1]; c += sm[w][2]; d += sm[w][3]; }
    out[0] = (float)(0.1 * (a / (bsum + 1e-8) + c / (d + 1e-8)));
  }
}

extern "C" void kernel_launch(void* const* d_in, const int* in_sizes, int n_in,
                              void* d_out, int out_size, void* d_ws, size_t ws_size,
                              hipStream_t stream) {
  const float* feats_view1 = (const float*)d_in[0];
  const float* pos_feats1  = (const float*)d_in[1];
  const float* pos_feats2  = (const float*)d_in[2];
  const float* pl1 = (const float*)d_in[3];
  const float* pl2 = (const float*)d_in[4];
  const float* npl = (const float*)d_in[5];

  char* ws = (char*)d_ws;
  ushort* Bt        = (ushort*)(ws + 0);          // 2*57600*128*2 = 29,491,200
  ushort* At        = (ushort*)(ws + 29491200);   //  1,843,200
  int*    nlab      = (int*)   (ws + 31334400);   //    460,800
  int*    lab1      = (int*)   (ws + 31795200);   //     28,800
  float*  mask1     = (float*) (ws + 31824000);   //     28,800
  float*  pos1      = (float*) (ws + 31852800);   //     28,800
  float*  neg_logits= (float*) (ws + 31881600);   //     28,800

  // fused prep: B transpose (+neg labels), A transpose, anchor work
  prep_kernel<<<dim3(N_ / 64 + 57 + 15, NB), 256, 0, stream>>>(
      feats_view1, Bt, pos_feats1, At, npl, nlab,
      pl1, pl2, pos_feats2, lab1, mask1, pos1, neg_logits);
  gemm_kernel<<<dim3(PT, NSPLIT, NB), 256, 0, stream>>>(At, Bt, lab1, nlab, neg_logits);
  finalize_kernel<<<1, 256, 0, stream>>>(neg_logits, pos1, mask1, (float*)d_out);
}

// Round 6
// 274.730 us; speedup vs baseline: 6.3892x; 1.4712x over previous
//
#include <hip/hip_runtime.h>
#include <string.h>

#define D_ 128
#define P_ 3600
#define N_ 57600
#define C_ 19
#define NB 2
#define NSPLIT 30
#define CHPB 15      // chunks per block = 450/30
#define PT 29        // ceil(3600/128)

typedef short bf16x8 __attribute__((ext_vector_type(8)));
typedef float f32x4 __attribute__((ext_vector_type(4)));

__device__ __forceinline__ ushort f2bf(float x) {
  unsigned u = __float_as_uint(x);
  u = (u + 0x7fffu + ((u >> 16) & 1u)) >> 16;   // RNE to bf16
  return (ushort)u;
}

// async global->LDS DMA, 16B per lane; LDS dest = wave-uniform base + lane*16
__device__ __forceinline__ void gload_lds16(const void* g, void* l) {
  __builtin_amdgcn_global_load_lds(
      (const __attribute__((address_space(1))) unsigned int*)g,
      (__attribute__((address_space(3))) unsigned int*)l, 16, 0, 0);
}

// ---- prep: fused B transpose (+neg labels), A transpose, and anchor work ----
// grid.x = 900 (B tiles) + 57 (A tiles) + 15 (anchor blocks); grid.y = NB
__global__ void prep_kernel(const float* __restrict__ XB, ushort* __restrict__ YB,
                            const float* __restrict__ XA, ushort* __restrict__ YA,
                            const float* __restrict__ npl, int* __restrict__ nlab,
                            const float* __restrict__ pl1, const float* __restrict__ pl2,
                            const float* __restrict__ f2,
                            int* __restrict__ lab1, float* __restrict__ mask1,
                            float* __restrict__ pos1, float* __restrict__ neg_logits) {
  __shared__ float T[64][129];
  const int b = blockIdx.y;
  const int tid = threadIdx.x;

  if (blockIdx.x >= N_ / 64 + 57) {
    // ---- anchor path: labels1, mask1, pos1, zero neg_logits ----
    int p = (blockIdx.x - (N_ / 64 + 57)) * 256 + tid;
    if (p >= P_) return;
    const float* a1 = pl1 + (size_t)b * C_ * P_ + p;
    const float* a2 = pl2 + (size_t)b * C_ * P_ + p;
    float best = a1[0]; int bi = 0;
    int mfirst = ((a1[0] < a2[0]) && (a2[0] > 0.75f)) ? 0 : -1;
#pragma unroll
    for (int c = 1; c < C_; ++c) {
      float v1 = a1[(size_t)c * P_], v2 = a2[(size_t)c * P_];
      if (v1 > best) { best = v1; bi = c; }
      if (mfirst < 0 && (v1 < v2) && (v2 > 0.75f)) mfirst = c;
    }
    lab1[b * P_ + p] = bi;
    mask1[b * P_ + p] = (mfirst < 0) ? 0.0f : (float)mfirst;
    neg_logits[b * P_ + p] = 0.0f;
    const float* g1 = XA + (size_t)b * D_ * P_ + p;
    const float* g2 = f2 + (size_t)b * D_ * P_ + p;
    float s = 0.f;
#pragma unroll 8
    for (int d = 0; d < D_; ++d) s += g1[(size_t)d * P_] * g2[(size_t)d * P_];
    pos1[b * P_ + p] = s * 10.0f;   // /TEMP
    return;
  }

  // ---- transpose path: [D,M] fp32 -> [M,128] bf16 (pre-scaled) ----
  const bool isB = blockIdx.x < (N_ / 64);
  const int M = isB ? N_ : P_;
  const float scale = isB ? 1.0f : 14.4269504089f;  // A pre-scaled by (1/TEMP)*log2(e)
  const int nbase = (isB ? blockIdx.x : (blockIdx.x - N_ / 64)) * 64;
  const float* Xb = (isB ? XB : XA) + (size_t)b * D_ * M;
  ushort* Yb = (isB ? YB : YA) + (size_t)b * M * D_;
  const int nl = tid & 63;
  const int dw = tid >> 6;
#pragma unroll
  for (int i = 0; i < 32; ++i) {
    int d = i * 4 + dw;
    int gn = nbase + nl; if (gn >= M) gn = M - 1;
    T[nl][d] = Xb[(size_t)d * M + gn];
  }
  __syncthreads();
  const int d0 = (tid & 31) * 4;
#pragma unroll
  for (int i = 0; i < 8; ++i) {
    int n = i * 8 + (tid >> 5);
    int gn = nbase + n;
    if (gn < M) {
      ushort4 u;
      u.x = f2bf(T[n][d0 + 0] * scale);
      u.y = f2bf(T[n][d0 + 1] * scale);
      u.z = f2bf(T[n][d0 + 2] * scale);
      u.w = f2bf(T[n][d0 + 3] * scale);
      *(ushort4*)(Yb + (size_t)gn * D_ + d0) = u;
    }
  }
  if (isB && tid < 64) {
    int gn = nbase + tid;
    const float* base = npl + (size_t)b * C_ * N_ + gn;
    float best = base[0]; int bi = 0;
#pragma unroll
    for (int c = 1; c < C_; ++c) {
      float v = base[(size_t)c * N_];
      if (v > best) { best = v; bi = c; }
    }
    nlab[b * N_ + gn] = bi;
  }
}

// ---- fused GEMM + exp + mask + row-sum ----
// 1D grid of 8*29*8=1856 blocks, XCD-affinity encoded: group g=(y,sample) has all its
// 29 ptile-blocks at flat%8==g%8 -> same XCD (HW round-robin, m09) -> its disjoint
// 480 KiB B-range is fetched once into that XCD's L2 and shared 29 ways.
// LDS: 2x32 KiB B double-buffer (A staged through buf0 once, af held in AGPRs).
// DMA for chunk j+1 issued AFTER the barrier -> full compute-j phase of cover before
// the next barrier's vmcnt(0) drain. __launch_bounds__(256,2): VGPR cap 256, no spill.
__global__ __launch_bounds__(256, 2) void gemm_kernel(
    const ushort* __restrict__ At, const ushort* __restrict__ Bt,
    const int* __restrict__ lab1g, const int* __restrict__ nlabg,
    float* __restrict__ neg_logits) {
  __shared__ __attribute__((aligned(16))) ushort Bs[2][128 * 128];
  const int flat = blockIdx.x;
  const int xcd = flat & 7;
  const int rem = flat >> 3;
  const int slot = rem / PT;
  const int ptile = rem % PT;
  const int g = slot * 8 + xcd;
  if (g >= 2 * NSPLIT) return;          // 116 idle pad blocks
  const int y = g >> 1;
  const int b = g & 1;

  const int tid = threadIdx.x;
  const int wid = tid >> 6, lane = tid & 63;
  const int quad = lane >> 4, lm = lane & 15;
  const int qr = wid & 1, qc = wid >> 1;
  const ushort* Atb = At + (size_t)b * P_ * D_;
  const ushort* Btb = Bt + (size_t)b * N_ * D_;
  const int* lab1 = lab1g + b * P_;
  const int* nlab = nlabg + b * N_;

  const int row4 = wid * 4 + (lane >> 4);   // staging row within each 16-row group
  const int cc = lane & 15;
  const int swz = cc ^ (row4 & 7);          // involutive xor swizzle on the global side

  // ---- stage A tile into LDS buf0 via DMA (rows clamped for the partial last tile) ----
#pragma unroll
  for (int i = 0; i < 8; ++i) {
    int row = i * 16 + row4;
    int p = ptile * 128 + row; if (p > P_ - 1) p = P_ - 1;
    gload_lds16(Atb + (size_t)p * D_ + swz * 8, &Bs[0][(i * 16 + wid * 4) * 128]);
  }
  __syncthreads();

  // ---- A fragments LDS -> registers (held for the whole kernel) ----
  bf16x8 af[4][4];
#pragma unroll
  for (int r = 0; r < 4; ++r) {
    int row = qr * 64 + r * 16 + lm;
#pragma unroll
    for (int k0 = 0; k0 < 4; ++k0) {
      int ch = (k0 * 4 + quad) ^ (row & 7);
      af[r][k0] = *(const bf16x8*)(&Bs[0][row * 128 + ch * 8]);
    }
  }

  // labels of my 16 output rows
  int labp[16];
#pragma unroll
  for (int r = 0; r < 4; ++r)
#pragma unroll
    for (int gg = 0; gg < 4; ++gg) {
      int p = ptile * 128 + qr * 64 + r * 16 + quad * 4 + gg;
      labp[r * 4 + gg] = lab1[p > P_ - 1 ? P_ - 1 : p];
    }

  float rsum[16];
#pragma unroll
  for (int i = 0; i < 16; ++i) rsum[i] = 0.f;
  const f32x4 zero4 = {0.f, 0.f, 0.f, 0.f};

  const int c0 = y * CHPB;
  const int c1 = c0 + CHPB;
  const ushort* srcB = Btb + (size_t)row4 * D_ + swz * 8;

  __syncthreads();   // all waves' af reads retired before buf0 is overwritten
  // prefetch first chunk into buf0 (cold: drained by first loop barrier)
  {
    const ushort* s = srcB + (size_t)c0 * 128 * D_;
#pragma unroll
    for (int i = 0; i < 8; ++i)
      gload_lds16(s + (size_t)i * 16 * D_, &Bs[0][(i * 16 + wid * 4) * 128]);
  }

  for (int j = c0; j < c1; ++j) {
    const int p = (j - c0) & 1;
    const int nbase = j * 128;
    __syncthreads();   // drains DMA for chunk j (covered by compute j-1)
    if (j + 1 < c1) {  // prefetch j+1 into the other buffer, covered by compute j
      const ushort* s = srcB + (size_t)(j + 1) * 128 * D_;
#pragma unroll
      for (int i = 0; i < 8; ++i)
        gload_lds16(s + (size_t)i * 16 * D_, &Bs[p ^ 1][(i * 16 + wid * 4) * 128]);
    }

#pragma unroll
    for (int c = 0; c < 4; ++c) {
      const int row = qc * 64 + c * 16 + lm;
      const int nl = nlab[nbase + row];
      f32x4 acc[4];
      {
        int ch = quad ^ (row & 7);
        bf16x8 bf = *(const bf16x8*)(&Bs[p][row * 128 + ch * 8]);
#pragma unroll
        for (int r = 0; r < 4; ++r)
          acc[r] = __builtin_amdgcn_mfma_f32_16x16x32_bf16(af[r][0], bf, zero4, 0, 0, 0);
      }
#pragma unroll
      for (int k0 = 1; k0 < 4; ++k0) {
        int ch = (k0 * 4 + quad) ^ (row & 7);
        bf16x8 bf = *(const bf16x8*)(&Bs[p][row * 128 + ch * 8]);
#pragma unroll
        for (int r = 0; r < 4; ++r)
          acc[r] = __builtin_amdgcn_mfma_f32_16x16x32_bf16(af[r][k0], bf, acc[r], 0, 0, 0);
      }
      // epilogue: exp2 (A pre-scaled by 10*log2e) + label mask + row sums
#pragma unroll
      for (int r = 0; r < 4; ++r)
#pragma unroll
        for (int gg = 0; gg < 4; ++gg) {
          float e = __builtin_amdgcn_exp2f(acc[r][gg]);
          rsum[r * 4 + gg] += (labp[r * 4 + gg] != nl) ? e : 0.f;
        }
    }
  }

  // reduce over the 16 lanes sharing a column group
#pragma unroll
  for (int i = 0; i < 16; ++i) {
    float v = rsum[i];
    v += __shfl_xor(v, 1);
    v += __shfl_xor(v, 2);
    v += __shfl_xor(v, 4);
    v += __shfl_xor(v, 8);
    rsum[i] = v;
  }
  if (lm == 0) {
#pragma unroll
    for (int r = 0; r < 4; ++r)
#pragma unroll
      for (int gg = 0; gg < 4; ++gg) {
        int p = ptile * 128 + qr * 64 + r * 16 + quad * 4 + gg;
        if (p < P_) atomicAdd(&neg_logits[b * P_ + p], rsum[r * 4 + gg]);
      }
  }
}

// ---- finalize: weighted means, scalar out ----
__global__ void finalize_kernel(const float* __restrict__ neg_logits,
                                const float* __restrict__ pos1,
                                const float* __restrict__ mask1,
                                float* __restrict__ out) {
  double s1[2] = {0.0, 0.0}, s2[2] = {0.0, 0.0};
  for (int idx = threadIdx.x; idx < NB * P_; idx += 256) {
    int b = idx / P_;
    float ne = neg_logits[idx];
    float pe = __expf(pos1[idx]);
    float l = -logf(pe / (pe + ne + 1e-8f) + 1e-8f);
    float w = mask1[idx];
    s1[b] += (double)(w * l);
    s2[b] += (double)w;
  }
#pragma unroll
  for (int off = 32; off > 0; off >>= 1) {
    s1[0] += __shfl_down(s1[0], off);
    s2[0] += __shfl_down(s2[0], off);
    s1[1] += __shfl_down(s1[1], off);
    s2[1] += __shfl_down(s2[1], off);
  }
  __shared__ double sm[4][4];
  int wid = threadIdx.x >> 6, lane = threadIdx.x & 63;
  if (lane == 0) { sm[wid][0] = s1[0]; sm[wid][1] = s2[0]; sm[wid][2] = s1[1]; sm[wid][3] = s2[1]; }
  __syncthreads();
  if (threadIdx.x == 0) {
    double a = 0, bsum = 0, c = 0, d = 0;
    for (int w = 0; w < 4; ++w) { a += sm[w][0]; bsum += sm[w][1]; c += sm[w][2]; d += sm[w][3]; }
    out[0] = (float)(0.1 * (a / (bsum + 1e-8) + c / (d + 1e-8)));
  }
}

extern "C" void kernel_launch(void* const* d_in, const int* in_sizes, int n_in,
                              void* d_out, int out_size, void* d_ws, size_t ws_size,
                              hipStream_t stream) {
  const float* feats_view1 = (const float*)d_in[0];
  const float* pos_feats1  = (const float*)d_in[1];
  const float* pos_feats2  = (const float*)d_in[2];
  const float* pl1 = (const float*)d_in[3];
  const float* pl2 = (const float*)d_in[4];
  const float* npl = (const float*)d_in[5];

  char* ws = (char*)d_ws;
  ushort* Bt        = (ushort*)(ws + 0);          // 2*57600*128*2 = 29,491,200
  ushort* At        = (ushort*)(ws + 29491200);   //  1,843,200
  int*    nlab      = (int*)   (ws + 31334400);   //    460,800
  int*    lab1      = (int*)   (ws + 31795200);   //     28,800
  float*  mask1     = (float*) (ws + 31824000);   //     28,800
  float*  pos1      = (float*) (ws + 31852800);   //     28,800
  float*  neg_logits= (float*) (ws + 31881600);   //     28,800

  // fused prep: B transpose (+neg labels), A transpose, anchor work
  prep_kernel<<<dim3(N_ / 64 + 57 + 15, NB), 256, 0, stream>>>(
      feats_view1, Bt, pos_feats1, At, npl, nlab,
      pl1, pl2, pos_feats2, lab1, mask1, pos1, neg_logits);
  gemm_kernel<<<dim3(8 * PT * 8), 256, 0, stream>>>(At, Bt, lab1, nlab, neg_logits);
  finalize_kernel<<<1, 256, 0, stream>>>(neg_logits, pos1, mask1, (float*)d_out);
}

// Round 7
// 273.668 us; speedup vs baseline: 6.4140x; 1.0039x over previous
//
#include <hip/hip_runtime.h>
#include <string.h>

#define D_ 128
#define P_ 3600
#define N_ 57600
#define C_ 19
#define NB 2
#define NSPLIT 30
#define CHPB 15      // chunks per block = 450/30
#define PT 29        // ceil(3600/128)

typedef short bf16x8 __attribute__((ext_vector_type(8)));
typedef float f32x4 __attribute__((ext_vector_type(4)));

__device__ __forceinline__ ushort f2bf(float x) {
  unsigned u = __float_as_uint(x);
  u = (u + 0x7fffu + ((u >> 16) & 1u)) >> 16;   // RNE to bf16
  return (ushort)u;
}

// async global->LDS DMA, 16B per lane; LDS dest = wave-uniform base + lane*16
__device__ __forceinline__ void gload_lds16(const void* g, void* l) {
  __builtin_amdgcn_global_load_lds(
      (const __attribute__((address_space(1))) unsigned int*)g,
      (__attribute__((address_space(3))) unsigned int*)l, 16, 0, 0);
}

// ---- prep: fused B transpose (+neg labels), A transpose, and anchor work ----
// grid.x = 900 (B tiles) + 57 (A tiles) + 15 (anchor blocks); grid.y = NB
__global__ void prep_kernel(const float* __restrict__ XB, ushort* __restrict__ YB,
                            const float* __restrict__ XA, ushort* __restrict__ YA,
                            const float* __restrict__ npl, int* __restrict__ nlab,
                            const float* __restrict__ pl1, const float* __restrict__ pl2,
                            const float* __restrict__ f2,
                            int* __restrict__ lab1, float* __restrict__ mask1,
                            float* __restrict__ pos1, float* __restrict__ neg_logits) {
  __shared__ float T[64][129];
  const int b = blockIdx.y;
  const int tid = threadIdx.x;

  if (blockIdx.x >= N_ / 64 + 57) {
    // ---- anchor path: labels1, mask1, pos1, zero neg_logits ----
    int p = (blockIdx.x - (N_ / 64 + 57)) * 256 + tid;
    if (p >= P_) return;
    const float* a1 = pl1 + (size_t)b * C_ * P_ + p;
    const float* a2 = pl2 + (size_t)b * C_ * P_ + p;
    float best = a1[0]; int bi = 0;
    int mfirst = ((a1[0] < a2[0]) && (a2[0] > 0.75f)) ? 0 : -1;
#pragma unroll
    for (int c = 1; c < C_; ++c) {
      float v1 = a1[(size_t)c * P_], v2 = a2[(size_t)c * P_];
      if (v1 > best) { best = v1; bi = c; }
      if (mfirst < 0 && (v1 < v2) && (v2 > 0.75f)) mfirst = c;
    }
    lab1[b * P_ + p] = bi;
    mask1[b * P_ + p] = (mfirst < 0) ? 0.0f : (float)mfirst;
    neg_logits[b * P_ + p] = 0.0f;
    const float* g1 = XA + (size_t)b * D_ * P_ + p;
    const float* g2 = f2 + (size_t)b * D_ * P_ + p;
    float s = 0.f;
#pragma unroll 8
    for (int d = 0; d < D_; ++d) s += g1[(size_t)d * P_] * g2[(size_t)d * P_];
    pos1[b * P_ + p] = s * 10.0f;   // /TEMP
    return;
  }

  // ---- transpose path: [D,M] fp32 -> [M,128] bf16 (pre-scaled), float4 reads ----
  const bool isB = blockIdx.x < (N_ / 64);
  const int M = isB ? N_ : P_;
  const float scale = isB ? 1.0f : 14.4269504089f;  // A pre-scaled by (1/TEMP)*log2(e)
  const int nbase = (isB ? blockIdx.x : (blockIdx.x - N_ / 64)) * 64;
  const float* Xb = (isB ? XB : XA) + (size_t)b * D_ * M;
  ushort* Yb = (isB ? YB : YA) + (size_t)b * M * D_;
  const int nq = tid & 15;      // 4-column group within the 64-col tile
  const int dr = tid >> 4;      // 16 d-rows per round
#pragma unroll
  for (int i = 0; i < 8; ++i) {
    int d = i * 16 + dr;
    int gn0 = nbase + nq * 4;
    if (gn0 > M - 4) gn0 = M - 4;           // partial last A tile: rows >=16 unused anyway
    float4 v = *(const float4*)(Xb + (size_t)d * M + gn0);
    T[nq * 4 + 0][d] = v.x;
    T[nq * 4 + 1][d] = v.y;
    T[nq * 4 + 2][d] = v.z;
    T[nq * 4 + 3][d] = v.w;
  }
  __syncthreads();
  const int d0 = (tid & 31) * 4;
#pragma unroll
  for (int i = 0; i < 8; ++i) {
    int n = i * 8 + (tid >> 5);
    int gn = nbase + n;
    if (gn < M) {
      ushort4 u;
      u.x = f2bf(T[n][d0 + 0] * scale);
      u.y = f2bf(T[n][d0 + 1] * scale);
      u.z = f2bf(T[n][d0 + 2] * scale);
      u.w = f2bf(T[n][d0 + 3] * scale);
      *(ushort4*)(Yb + (size_t)gn * D_ + d0) = u;
    }
  }
  if (isB && tid < 64) {
    int gn = nbase + tid;
    const float* base = npl + (size_t)b * C_ * N_ + gn;
    float best = base[0]; int bi = 0;
#pragma unroll
    for (int c = 1; c < C_; ++c) {
      float v = base[(size_t)c * N_];
      if (v > best) { best = v; bi = c; }
    }
    nlab[b * N_ + gn] = bi;
  }
}

// ---- fused GEMM + exp + mask + row-sum ----
// 1D grid of 1856 blocks x 512 threads (8 waves). XCD-affinity: group g=(y,sample)
// lives at flat%8==g%8 -> one XCD -> disjoint 480 KiB B-range fetched once into that
// L2 (R6: FETCH 656->18 MB). LDS: 2x32 KiB B dbuf, DMA prefetch issued post-barrier.
// 8 waves split rows 4-way (af[2][4]=32 AGPR) x cols 2-way: per-wave regs ~100 so
// __launch_bounds__(512,4) (cap 128) holds 2 blocks/CU = 16 waves/CU (2x R6).
__global__ __launch_bounds__(512, 4) void gemm_kernel(
    const ushort* __restrict__ At, const ushort* __restrict__ Bt,
    const int* __restrict__ lab1g, const int* __restrict__ nlabg,
    float* __restrict__ neg_logits) {
  __shared__ __attribute__((aligned(16))) ushort Bs[2][128 * 128];
  const int flat = blockIdx.x;
  const int xcd = flat & 7;
  const int rem = flat >> 3;
  const int slot = rem / PT;
  const int ptile = rem % PT;
  const int g = slot * 8 + xcd;
  if (g >= 2 * NSPLIT) return;          // 116 idle pad blocks
  const int y = g >> 1;
  const int b = g & 1;

  const int tid = threadIdx.x;
  const int wid = tid >> 6, lane = tid & 63;
  const int quad = lane >> 4, lm = lane & 15;
  const int qr = wid & 3;               // row quarter (32 rows)
  const int qc = wid >> 2;              // column half (64 cols)
  const ushort* Atb = At + (size_t)b * P_ * D_;
  const ushort* Btb = Bt + (size_t)b * N_ * D_;
  const int* lab1 = lab1g + b * P_;
  const int* nlab = nlabg + b * N_;

  const int row4 = wid * 4 + quad;      // staging row within each 32-row group (0..31)
  const int cc = lane & 15;
  const int swz = cc ^ (row4 & 7);      // involutive xor swizzle on the global side

  // ---- stage A tile into LDS buf0 via DMA (rows clamped for the partial last tile) ----
#pragma unroll
  for (int i = 0; i < 4; ++i) {
    int row = i * 32 + row4;
    int p = ptile * 128 + row; if (p > P_ - 1) p = P_ - 1;
    gload_lds16(Atb + (size_t)p * D_ + swz * 8, &Bs[0][(i * 32 + wid * 4) * 128]);
  }
  __syncthreads();

  // ---- A fragments LDS -> registers (held for the whole kernel) ----
  bf16x8 af[2][4];
#pragma unroll
  for (int r = 0; r < 2; ++r) {
    int row = qr * 32 + r * 16 + lm;
#pragma unroll
    for (int k0 = 0; k0 < 4; ++k0) {
      int ch = (k0 * 4 + quad) ^ (row & 7);
      af[r][k0] = *(const bf16x8*)(&Bs[0][row * 128 + ch * 8]);
    }
  }

  // labels of my 8 output rows
  int labp[8];
#pragma unroll
  for (int r = 0; r < 2; ++r)
#pragma unroll
    for (int gg = 0; gg < 4; ++gg) {
      int p = ptile * 128 + qr * 32 + r * 16 + quad * 4 + gg;
      labp[r * 4 + gg] = lab1[p > P_ - 1 ? P_ - 1 : p];
    }

  float rsum[8];
#pragma unroll
  for (int i = 0; i < 8; ++i) rsum[i] = 0.f;
  const f32x4 zero4 = {0.f, 0.f, 0.f, 0.f};

  const int c0 = y * CHPB;
  const int c1 = c0 + CHPB;
  const ushort* srcB = Btb + (size_t)row4 * D_ + swz * 8;

  __syncthreads();   // all waves' af reads retired before buf0 is overwritten
  // prefetch first chunk into buf0 (cold: drained by first loop barrier)
  {
    const ushort* s = srcB + (size_t)c0 * 128 * D_;
#pragma unroll
    for (int i = 0; i < 4; ++i)
      gload_lds16(s + (size_t)i * 32 * D_, &Bs[0][(i * 32 + wid * 4) * 128]);
  }

  for (int j = c0; j < c1; ++j) {
    const int p = (j - c0) & 1;
    const int nbase = j * 128;
    __syncthreads();   // drains DMA for chunk j (covered by compute j-1)
    if (j + 1 < c1) {  // prefetch j+1 into the other buffer, covered by compute j
      const ushort* s = srcB + (size_t)(j + 1) * 128 * D_;
#pragma unroll
      for (int i = 0; i < 4; ++i)
        gload_lds16(s + (size_t)i * 32 * D_, &Bs[p ^ 1][(i * 32 + wid * 4) * 128]);
    }

#pragma unroll
    for (int c = 0; c < 4; ++c) {
      const int row = qc * 64 + c * 16 + lm;
      const int nl = nlab[nbase + row];
      f32x4 acc[2];
      {
        int ch = quad ^ (row & 7);
        bf16x8 bf = *(const bf16x8*)(&Bs[p][row * 128 + ch * 8]);
#pragma unroll
        for (int r = 0; r < 2; ++r)
          acc[r] = __builtin_amdgcn_mfma_f32_16x16x32_bf16(af[r][0], bf, zero4, 0, 0, 0);
      }
#pragma unroll
      for (int k0 = 1; k0 < 4; ++k0) {
        int ch = (k0 * 4 + quad) ^ (row & 7);
        bf16x8 bf = *(const bf16x8*)(&Bs[p][row * 128 + ch * 8]);
#pragma unroll
        for (int r = 0; r < 2; ++r)
          acc[r] = __builtin_amdgcn_mfma_f32_16x16x32_bf16(af[r][k0], bf, acc[r], 0, 0, 0);
      }
      // epilogue: exp2 (A pre-scaled by 10*log2e) + label mask + row sums
#pragma unroll
      for (int r = 0; r < 2; ++r)
#pragma unroll
        for (int gg = 0; gg < 4; ++gg) {
          float e = __builtin_amdgcn_exp2f(acc[r][gg]);
          rsum[r * 4 + gg] += (labp[r * 4 + gg] != nl) ? e : 0.f;
        }
    }
  }

  // reduce over the 16 lanes sharing a column group
#pragma unroll
  for (int i = 0; i < 8; ++i) {
    float v = rsum[i];
    v += __shfl_xor(v, 1);
    v += __shfl_xor(v, 2);
    v += __shfl_xor(v, 4);
    v += __shfl_xor(v, 8);
    rsum[i] = v;
  }
  if (lm == 0) {
#pragma unroll
    for (int r = 0; r < 2; ++r)
#pragma unroll
      for (int gg = 0; gg < 4; ++gg) {
        int p = ptile * 128 + qr * 32 + r * 16 + quad * 4 + gg;
        if (p < P_) atomicAdd(&neg_logits[b * P_ + p], rsum[r * 4 + gg]);
      }
  }
}

// ---- finalize: weighted means, scalar out ----
__global__ void finalize_kernel(const float* __restrict__ neg_logits,
                                const float* __restrict__ pos1,
                                const float* __restrict__ mask1,
                                float* __restrict__ out) {
  double s1[2] = {0.0, 0.0}, s2[2] = {0.0, 0.0};
  for (int idx = threadIdx.x; idx < NB * P_; idx += 256) {
    int b = idx / P_;
    float ne = neg_logits[idx];
    float pe = __expf(pos1[idx]);
    float l = -logf(pe / (pe + ne + 1e-8f) + 1e-8f);
    float w = mask1[idx];
    s1[b] += (double)(w * l);
    s2[b] += (double)w;
  }
#pragma unroll
  for (int off = 32; off > 0; off >>= 1) {
    s1[0] += __shfl_down(s1[0], off);
    s2[0] += __shfl_down(s2[0], off);
    s1[1] += __shfl_down(s1[1], off);
    s2[1] += __shfl_down(s2[1], off);
  }
  __shared__ double sm[4][4];
  int wid = threadIdx.x >> 6, lane = threadIdx.x & 63;
  if (lane == 0) { sm[wid][0] = s1[0]; sm[wid][1] = s2[0]; sm[wid][2] = s1[1]; sm[wid][3] = s2[1]; }
  __syncthreads();
  if (threadIdx.x == 0) {
    double a = 0, bsum = 0, c = 0, d = 0;
    for (int w = 0; w < 4; ++w) { a += sm[w][0]; bsum += sm[w][1]; c += sm[w][2]; d += sm[w][3]; }
    out[0] = (float)(0.1 * (a / (bsum + 1e-8) + c / (d + 1e-8)));
  }
}

extern "C" void kernel_launch(void* const* d_in, const int* in_sizes, int n_in,
                              void* d_out, int out_size, void* d_ws, size_t ws_size,
                              hipStream_t stream) {
  const float* feats_view1 = (const float*)d_in[0];
  const float* pos_feats1  = (const float*)d_in[1];
  const float* pos_feats2  = (const float*)d_in[2];
  const float* pl1 = (const float*)d_in[3];
  const float* pl2 = (const float*)d_in[4];
  const float* npl = (const float*)d_in[5];

  char* ws = (char*)d_ws;
  ushort* Bt        = (ushort*)(ws + 0);          // 2*57600*128*2 = 29,491,200
  ushort* At        = (ushort*)(ws + 29491200);   //  1,843,200
  int*    nlab      = (int*)   (ws + 31334400);   //    460,800
  int*    lab1      = (int*)   (ws + 31795200);   //     28,800
  float*  mask1     = (float*) (ws + 31824000);   //     28,800
  float*  pos1      = (float*) (ws + 31852800);   //     28,800
  float*  neg_logits= (float*) (ws + 31881600);   //     28,800

  // fused prep: B transpose (+neg labels), A transpose, anchor work
  prep_kernel<<<dim3(N_ / 64 + 57 + 15, NB), 256, 0, stream>>>(
      feats_view1, Bt, pos_feats1, At, npl, nlab,
      pl1, pl2, pos_feats2, lab1, mask1, pos1, neg_logits);
  gemm_kernel<<<dim3(8 * PT * 8), 512, 0, stream>>>(At, Bt, lab1, nlab, neg_logits);
  finalize_kernel<<<1, 256, 0, stream>>>(neg_logits, pos1, mask1, (float*)d_out);
}

// Round 8
// 270.744 us; speedup vs baseline: 6.4832x; 1.0108x over previous
//
#include <hip/hip_runtime.h>
#include <string.h>

#define D_ 128
#define P_ 3600
#define N_ 57600
#define C_ 19
#define NB 2
#define NSPLIT 26
#define TOTCH 450    // 57600/128 column chunks; ~17.3 chunks per block (uneven split)
#define PT 29        // ceil(3600/128)

typedef short bf16x8 __attribute__((ext_vector_type(8)));
typedef float f32x4 __attribute__((ext_vector_type(4)));

__device__ __forceinline__ ushort f2bf(float x) {
  unsigned u = __float_as_uint(x);
  u = (u + 0x7fffu + ((u >> 16) & 1u)) >> 16;   // RNE to bf16
  return (ushort)u;
}

// async global->LDS DMA, 16B per lane; LDS dest = wave-uniform base + lane*16
__device__ __forceinline__ void gload_lds16(const void* g, void* l) {
  __builtin_amdgcn_global_load_lds(
      (const __attribute__((address_space(1))) unsigned int*)g,
      (__attribute__((address_space(3))) unsigned int*)l, 16, 0, 0);
}

// ---- prep: fused B transpose (+neg labels), A transpose, and anchor work ----
// grid.x = 900 (B tiles) + 57 (A tiles) + 15 (anchor blocks); grid.y = NB
__global__ void prep_kernel(const float* __restrict__ XB, ushort* __restrict__ YB,
                            const float* __restrict__ XA, ushort* __restrict__ YA,
                            const float* __restrict__ npl, int* __restrict__ nlab,
                            const float* __restrict__ pl1, const float* __restrict__ pl2,
                            const float* __restrict__ f2,
                            int* __restrict__ lab1, float* __restrict__ mask1,
                            float* __restrict__ pos1, float* __restrict__ neg_logits) {
  __shared__ float T[64][129];
  const int b = blockIdx.y;
  const int tid = threadIdx.x;

  if (blockIdx.x >= N_ / 64 + 57) {
    // ---- anchor path: labels1, mask1, pos1, zero neg_logits ----
    int p = (blockIdx.x - (N_ / 64 + 57)) * 256 + tid;
    if (p >= P_) return;
    const float* a1 = pl1 + (size_t)b * C_ * P_ + p;
    const float* a2 = pl2 + (size_t)b * C_ * P_ + p;
    float best = a1[0]; int bi = 0;
    int mfirst = ((a1[0] < a2[0]) && (a2[0] > 0.75f)) ? 0 : -1;
#pragma unroll
    for (int c = 1; c < C_; ++c) {
      float v1 = a1[(size_t)c * P_], v2 = a2[(size_t)c * P_];
      if (v1 > best) { best = v1; bi = c; }
      if (mfirst < 0 && (v1 < v2) && (v2 > 0.75f)) mfirst = c;
    }
    lab1[b * P_ + p] = bi;
    mask1[b * P_ + p] = (mfirst < 0) ? 0.0f : (float)mfirst;
    neg_logits[b * P_ + p] = 0.0f;
    const float* g1 = XA + (size_t)b * D_ * P_ + p;
    const float* g2 = f2 + (size_t)b * D_ * P_ + p;
    float s = 0.f;
#pragma unroll 8
    for (int d = 0; d < D_; ++d) s += g1[(size_t)d * P_] * g2[(size_t)d * P_];
    pos1[b * P_ + p] = s * 10.0f;   // /TEMP
    return;
  }

  // ---- transpose path: [D,M] fp32 -> [M,128] bf16 (pre-scaled), float4 reads ----
  const bool isB = blockIdx.x < (N_ / 64);
  const int M = isB ? N_ : P_;
  const float scale = isB ? 1.0f : 14.4269504089f;  // A pre-scaled by (1/TEMP)*log2(e)
  const int nbase = (isB ? blockIdx.x : (blockIdx.x - N_ / 64)) * 64;
  const float* Xb = (isB ? XB : XA) + (size_t)b * D_ * M;
  ushort* Yb = (isB ? YB : YA) + (size_t)b * M * D_;
  const int nq = tid & 15;      // 4-column group within the 64-col tile
  const int dr = tid >> 4;      // 16 d-rows per round
#pragma unroll
  for (int i = 0; i < 8; ++i) {
    int d = i * 16 + dr;
    int gn0 = nbase + nq * 4;
    if (gn0 > M - 4) gn0 = M - 4;
    float4 v = *(const float4*)(Xb + (size_t)d * M + gn0);
    T[nq * 4 + 0][d] = v.x;
    T[nq * 4 + 1][d] = v.y;
    T[nq * 4 + 2][d] = v.z;
    T[nq * 4 + 3][d] = v.w;
  }
  __syncthreads();
  const int d0 = (tid & 31) * 4;
#pragma unroll
  for (int i = 0; i < 8; ++i) {
    int n = i * 8 + (tid >> 5);
    int gn = nbase + n;
    if (gn < M) {
      ushort4 u;
      u.x = f2bf(T[n][d0 + 0] * scale);
      u.y = f2bf(T[n][d0 + 1] * scale);
      u.z = f2bf(T[n][d0 + 2] * scale);
      u.w = f2bf(T[n][d0 + 3] * scale);
      *(ushort4*)(Yb + (size_t)gn * D_ + d0) = u;
    }
  }
  if (isB && tid < 64) {
    int gn = nbase + tid;
    const float* base = npl + (size_t)b * C_ * N_ + gn;
    float best = base[0]; int bi = 0;
#pragma unroll
    for (int c = 1; c < C_; ++c) {
      float v = base[(size_t)c * N_];
      if (v > best) { best = v; bi = c; }
    }
    nlab[b * N_ + gn] = bi;
  }
}

// ---- fused GEMM + exp + mask + row-sum ----
// 256 threads (4 waves, R=2 row-split x C=2 col-split: B LDS reads = 64 KiB/chunk,
// HALF of R7's 8-wave layout -> the dominant LDS pipe drops ~2x). LDS = 2 x 16 KiB
// half-chunk ping-pong (32 KiB total) -> 3 blocks/CU at (256,3) (cap 170, ~150 live,
// R4-proven no-spill). DMA prefetch of half t+1 issued post-barrier; half t's compute
// (~600 cyc) covers the L2-hit drain. XCD affinity kept (R6: FETCH 656->18 MB).
// NSPLIT=26 -> 1508 active blocks ~= 1.96 waves of 768 slots (no near-empty tail wave).
__global__ __launch_bounds__(256, 3) void gemm_kernel(
    const ushort* __restrict__ At, const ushort* __restrict__ Bt,
    const int* __restrict__ lab1g, const int* __restrict__ nlabg,
    float* __restrict__ neg_logits) {
  __shared__ __attribute__((aligned(16))) ushort Sh[2][64 * 128];
  const int flat = blockIdx.x;
  const int xcd = flat & 7;
  const int rem = flat >> 3;
  const int slot = rem / PT;
  const int ptile = rem % PT;
  const int g = slot * 8 + xcd;
  if (g >= 2 * NSPLIT) return;          // idle pad blocks
  const int y = g >> 1;
  const int b = g & 1;

  const int tid = threadIdx.x;
  const int wid = tid >> 6, lane = tid & 63;
  const int quad = lane >> 4, lm = lane & 15;
  const int qr = wid & 1, qc = wid >> 1;
  const ushort* Atb = At + (size_t)b * P_ * D_;
  const ushort* Btb = Bt + (size_t)b * N_ * D_;
  const int* lab1 = lab1g + b * P_;
  const int* nlab = nlabg + b * N_;

  const int row4 = wid * 4 + quad;      // staging row within each 16-row group (0..15)
  const int cc = lane & 15;
  const int swz = cc ^ (row4 & 7);      // involutive xor swizzle on the global side

  // ---- stage A tile (32 KiB across both halves) via DMA ----
#pragma unroll
  for (int i = 0; i < 8; ++i) {
    int row = i * 16 + row4;
    int p = ptile * 128 + row; if (p > P_ - 1) p = P_ - 1;
    gload_lds16(Atb + (size_t)p * D_ + swz * 8, &Sh[0][0] + (i * 16 + wid * 4) * 128);
  }
  __syncthreads();

  // ---- A fragments LDS -> registers (held for the whole kernel) ----
  bf16x8 af[4][4];
#pragma unroll
  for (int r = 0; r < 4; ++r) {
    int row = qr * 64 + r * 16 + lm;
#pragma unroll
    for (int k0 = 0; k0 < 4; ++k0) {
      int ch = (k0 * 4 + quad) ^ (row & 7);
      af[r][k0] = *(const bf16x8*)(&Sh[0][0] + row * 128 + ch * 8);
    }
  }

  // labels of my 16 output rows
  int labp[16];
#pragma unroll
  for (int r = 0; r < 4; ++r)
#pragma unroll
    for (int gg = 0; gg < 4; ++gg) {
      int p = ptile * 128 + qr * 64 + r * 16 + quad * 4 + gg;
      labp[r * 4 + gg] = lab1[p > P_ - 1 ? P_ - 1 : p];
    }

  float rsum[16];
#pragma unroll
  for (int i = 0; i < 16; ++i) rsum[i] = 0.f;
  const f32x4 zero4 = {0.f, 0.f, 0.f, 0.f};

  const int c0 = (y * TOTCH) / NSPLIT;
  const int c1 = ((y + 1) * TOTCH) / NSPLIT;
  const int Hh = (c1 - c0) * 2;         // 64-col halves to process
  const ushort* srcB = Btb + (size_t)(c0 * 128 + row4) * D_ + swz * 8;

  __syncthreads();   // all waves' af reads retired before the buffers are overwritten
  // prefetch half 0 into buf 0 (cold: drained by first loop barrier, once per block)
#pragma unroll
  for (int i = 0; i < 4; ++i)
    gload_lds16(srcB + (size_t)(i * 16) * D_, &Sh[0][(i * 16 + wid * 4) * 128]);

  for (int t = 0; t < Hh; ++t) {
    const int buf = t & 1;
    __syncthreads();   // drains DMA for half t (covered by half t-1's compute)
    if (t + 1 < Hh) {  // prefetch half t+1 into the other buffer
      const ushort* s = srcB + (size_t)((t + 1) * 64) * D_;
#pragma unroll
      for (int i = 0; i < 4; ++i)
        gload_lds16(s + (size_t)(i * 16) * D_, &Sh[buf ^ 1][(i * 16 + wid * 4) * 128]);
    }

    const int nb64 = c0 * 128 + t * 64;  // global col base of this half
#pragma unroll
    for (int c = 0; c < 2; ++c) {
      const int brow = qc * 32 + c * 16 + lm;
      const int nl = nlab[nb64 + brow];
      f32x4 acc[4];
      {
        int ch = quad ^ (lm & 7);
        bf16x8 bf = *(const bf16x8*)(&Sh[buf][brow * 128 + ch * 8]);
#pragma unroll
        for (int r = 0; r < 4; ++r)
          acc[r] = __builtin_amdgcn_mfma_f32_16x16x32_bf16(af[r][0], bf, zero4, 0, 0, 0);
      }
#pragma unroll
      for (int k0 = 1; k0 < 4; ++k0) {
        int ch = (k0 * 4 + quad) ^ (lm & 7);
        bf16x8 bf = *(const bf16x8*)(&Sh[buf][brow * 128 + ch * 8]);
#pragma unroll
        for (int r = 0; r < 4; ++r)
          acc[r] = __builtin_amdgcn_mfma_f32_16x16x32_bf16(af[r][k0], bf, acc[r], 0, 0, 0);
      }
      // epilogue: exp2 (A pre-scaled by 10*log2e) + label mask + row sums
#pragma unroll
      for (int r = 0; r < 4; ++r)
#pragma unroll
        for (int gg = 0; gg < 4; ++gg) {
          float e = __builtin_amdgcn_exp2f(acc[r][gg]);
          rsum[r * 4 + gg] += (labp[r * 4 + gg] != nl) ? e : 0.f;
        }
    }
  }

  // reduce over the 16 lanes sharing a column group
#pragma unroll
  for (int i = 0; i < 16; ++i) {
    float v = rsum[i];
    v += __shfl_xor(v, 1);
    v += __shfl_xor(v, 2);
    v += __shfl_xor(v, 4);
    v += __shfl_xor(v, 8);
    rsum[i] = v;
  }
  if (lm == 0) {
#pragma unroll
    for (int r = 0; r < 4; ++r)
#pragma unroll
      for (int gg = 0; gg < 4; ++gg) {
        int p = ptile * 128 + qr * 64 + r * 16 + quad * 4 + gg;
        if (p < P_) atomicAdd(&neg_logits[b * P_ + p], rsum[r * 4 + gg]);
      }
  }
}

// ---- finalize: weighted means, scalar out ----
__global__ void finalize_kernel(const float* __restrict__ neg_logits,
                                const float* __restrict__ pos1,
                                const float* __restrict__ mask1,
                                float* __restrict__ out) {
  double s1[2] = {0.0, 0.0}, s2[2] = {0.0, 0.0};
  for (int idx = threadIdx.x; idx < NB * P_; idx += 256) {
    int b = idx / P_;
    float ne = neg_logits[idx];
    float pe = __expf(pos1[idx]);
    float l = -logf(pe / (pe + ne + 1e-8f) + 1e-8f);
    float w = mask1[idx];
    s1[b] += (double)(w * l);
    s2[b] += (double)w;
  }
#pragma unroll
  for (int off = 32; off > 0; off >>= 1) {
    s1[0] += __shfl_down(s1[0], off);
    s2[0] += __shfl_down(s2[0], off);
    s1[1] += __shfl_down(s1[1], off);
    s2[1] += __shfl_down(s2[1], off);
  }
  __shared__ double sm[4][4];
  int wid = threadIdx.x >> 6, lane = threadIdx.x & 63;
  if (lane == 0) { sm[wid][0] = s1[0]; sm[wid][1] = s2[0]; sm[wid][2] = s1[1]; sm[wid][3] = s2[1]; }
  __syncthreads();
  if (threadIdx.x == 0) {
    double a = 0, bsum = 0, c = 0, d = 0;
    for (int w = 0; w < 4; ++w) { a += sm[w][0]; bsum += sm[w][1]; c += sm[w][2]; d += sm[w][3]; }
    out[0] = (float)(0.1 * (a / (bsum + 1e-8) + c / (d + 1e-8)));
  }
}

extern "C" void kernel_launch(void* const* d_in, const int* in_sizes, int n_in,
                              void* d_out, int out_size, void* d_ws, size_t ws_size,
                              hipStream_t stream) {
  const float* feats_view1 = (const float*)d_in[0];
  const float* pos_feats1  = (const float*)d_in[1];
  const float* pos_feats2  = (const float*)d_in[2];
  const float* pl1 = (const float*)d_in[3];
  const float* pl2 = (const float*)d_in[4];
  const float* npl = (const float*)d_in[5];

  char* ws = (char*)d_ws;
  ushort* Bt        = (ushort*)(ws + 0);          // 2*57600*128*2 = 29,491,200
  ushort* At        = (ushort*)(ws + 29491200);   //  1,843,200
  int*    nlab      = (int*)   (ws + 31334400);   //    460,800
  int*    lab1      = (int*)   (ws + 31795200);   //     28,800
  float*  mask1     = (float*) (ws + 31824000);   //     28,800
  float*  pos1      = (float*) (ws + 31852800);   //     28,800
  float*  neg_logits= (float*) (ws + 31881600);   //     28,800

  // fused prep: B transpose (+neg labels), A transpose, anchor work
  prep_kernel<<<dim3(N_ / 64 + 57 + 15, NB), 256, 0, stream>>>(
      feats_view1, Bt, pos_feats1, At, npl, nlab,
      pl1, pl2, pos_feats2, lab1, mask1, pos1, neg_logits);
  // grid: 8 xcd-slots * ceil(52/8)=7 group-slots * 29 ptiles = 1624 blocks (1508 active)
  gemm_kernel<<<dim3(8 * 7 * PT), 256, 0, stream>>>(At, Bt, lab1, nlab, neg_logits);
  finalize_kernel<<<1, 256, 0, stream>>>(neg_logits, pos1, mask1, (float*)d_out);
}